// Round 4
// baseline (2174.285 us; speedup 1.0000x reference)
//
#include <hip/hip_runtime.h>
#include <hip/hip_fp16.h>
#include <cstdint>

typedef _Float16 half8 __attribute__((ext_vector_type(8)));
typedef _Float16 half4 __attribute__((ext_vector_type(4)));
typedef float f32x4 __attribute__((ext_vector_type(4)));

#define MFMA_F16 __builtin_amdgcn_mfma_f32_16x16x32_f16
#define PIN(x)   asm volatile("" : "+v"(x))
// AGPR pin: forces the value into the accumulator file (gfx950 MFMA reads
// A/B straight from AGPRs). An asm output is non-rematerializable, so the
// compiler cannot turn this back into a per-iteration global reload.
#define PIN_A(x) asm volatile("" : "+a"(x))
#define LD_RLX(p)   __hip_atomic_load((p),  __ATOMIC_RELAXED, __HIP_MEMORY_SCOPE_AGENT)
#define LD_ACQ(p)   __hip_atomic_load((p),  __ATOMIC_ACQUIRE, __HIP_MEMORY_SCOPE_AGENT)
#define ST_REL(p,v) __hip_atomic_store((p),(v), __ATOMIC_RELEASE, __HIP_MEMORY_SCOPE_AGENT)

__device__ __forceinline__ float fast_rcp(float x){
#if __has_builtin(__builtin_amdgcn_rcpf)
  return __builtin_amdgcn_rcpf(x);
#else
  return 1.0f/x;
#endif
}
__device__ __forceinline__ float fast_exp2(float x){
#if __has_builtin(__builtin_amdgcn_exp2f)
  return __builtin_amdgcn_exp2f(x);
#else
  return exp2f(x);
#endif
}
__device__ __forceinline__ float sigm_f(float x){
  return fast_rcp(1.0f + fast_exp2(-1.44269504f*x));
}
__device__ __forceinline__ float tanh_fast(float x){
  float e = fast_exp2(-2.88539008f*x);            // e^(-2x)
  return fmaf(2.0f, fast_rcp(1.0f + e), -1.0f);   // 2/(1+e) - 1
}

// Weak barrier: LDS visibility only (no vmcnt drain -> global stores/loads
// stay in flight across steps). Strong barrier: full drain, used only at
// 16-step flag boundaries (cross-block release/acquire protocol unchanged).
__device__ __forceinline__ void bar_weak(){
  asm volatile("s_waitcnt lgkmcnt(0)" ::: "memory");
  __builtin_amdgcn_s_barrier();
  asm volatile("" ::: "memory");
}
__device__ __forceinline__ void bar_strong(){
  asm volatile("s_waitcnt vmcnt(0) lgkmcnt(0)" ::: "memory");
  __builtin_amdgcn_s_barrier();
  asm volatile("" ::: "memory");
}

// ---------------------------------------------------------------------------
// Phase A1: per-matrix max|w| (4 matrices of 768x256)
// ---------------------------------------------------------------------------
__global__ __launch_bounds__(256) void k_maxabs(
    const float* __restrict__ w0, const float* __restrict__ w1,
    const float* __restrict__ w2, const float* __restrict__ w3,
    int n, int* __restrict__ slots)
{
  const float* srcs[4] = {w0, w1, w2, w3};
  int m    = blockIdx.x >> 5;
  int part = blockIdx.x & 31;
  const float* w = srcs[m];
  float loc = 0.0f;
  for (int i = part*256 + threadIdx.x; i < n; i += 32*256)
    loc = fmaxf(loc, fabsf(w[i]));
  for (int off = 32; off; off >>= 1)
    loc = fmaxf(loc, __shfl_down(loc, off, 64));
  __shared__ float red[4];
  int wv = threadIdx.x >> 6;
  if ((threadIdx.x & 63) == 0) red[wv] = loc;
  __syncthreads();
  if (threadIdx.x == 0) {
    float mx = fmaxf(fmaxf(red[0], red[1]), fmaxf(red[2], red[3]));
    atomicMax(&slots[m], __float_as_int(mx));
  }
}

// ---------------------------------------------------------------------------
// Phase A2: fake-quantize -> fp16, MFMA-B-fragment-swizzled layout.
// ---------------------------------------------------------------------------
__global__ __launch_bounds__(256) void k_quant(
    const float* __restrict__ w0, const float* __restrict__ w1,
    const float* __restrict__ w2, const float* __restrict__ w3,
    const int* __restrict__ slots,
    _Float16* __restrict__ f0, _Float16* __restrict__ f1,
    _Float16* __restrict__ f2, _Float16* __restrict__ f3)
{
  const float* srcs[4] = {w0, w1, w2, w3};
  _Float16*    dsts[4] = {f0, f1, f2, f3};
  int idx = blockIdx.x*256 + threadIdx.x;
  int m = idx / 196608;
  int e = idx - m*196608;
  float scale = __int_as_float(slots[m]) * (1.0f/127.0f);
  float w = srcs[m][e];
  float q = rintf(w/scale) * scale;
  int g = e >> 8, k = e & 255;
  int tile = g >> 4, kb = k >> 5;
  int lane = ((k >> 3) & 3)*16 + (g & 15);
  int off  = (tile*8 + kb)*512 + lane*8 + (k & 7);
  dsts[m][off] = (_Float16)q;
}

// ---------------------------------------------------------------------------
// Fully fused pipeline: 96 blocks x 512 thr (8 waves).
//   role 0..15  : layer-1 GRU. Acquires gi1 groups via flag0,
//                 publishes h1seq progress via flag1.
//   role 16..31 : layer-2 GRU. Acquires gi2 via flag2, publishes flag3.
//   role 32..63 : gemm2 producers: h1seq @ W_ih2^T -> gi2 ring (64-step).
//   role 64..95 : gemm1 producers: x @ W_ih1^T -> gi1 (full buffer).
// Weight fragments are PIN_A'd into AGPRs (gfx950 unified file: 256-reg/wave
// cap at 8-wave blocks; consumer 176 AGPR + ~70 arch, producer 192 + ~60).
// Without this the compiler kept a 128-reg budget and re-fetched every
// fragment from L2/L3 each step (~360 KB/CU/step) — the measured 2.8 us/step.
// ---------------------------------------------------------------------------
__global__ __launch_bounds__(512, 1) void k_pipe(
    const float* __restrict__ x,
    const _Float16* __restrict__ wfih1, const float* __restrict__ bih1,
    _Float16* __restrict__ gi1, const _Float16* __restrict__ wfhh1,
    const float* __restrict__ bhh1, float* __restrict__ hc1,
    _Float16* __restrict__ h1seq,
    const _Float16* __restrict__ wfih2, const float* __restrict__ bih2,
    const float* __restrict__ bhh2, const _Float16* __restrict__ wfhh2,
    float* __restrict__ hc2, _Float16* __restrict__ gi2,
    int* __restrict__ flag0, int* __restrict__ flag1,
    int* __restrict__ flag2, int* __restrict__ flag3)
{
  __shared__ __align__(16) _Float16 hl[2][4096];   // 16 KB h dbuf (GRU roles)
  __shared__ __align__(16) _Float16 wn_l[16384];   // 32 KB: [w][nt][kb<2][512]
  const int role = blockIdx.x;
  const int tid  = threadIdx.x;
  const int w = tid >> 6, l = tid & 63, q = l >> 4, c16 = l & 15;

  if (role >= 64) {
    // ------------------- gemm1 producer: gi1 = fq(x) @ W_ih1^T + bias ------
    const int id = role - 64, bb = id >> 1, par = id & 1;
    const int b0 = bb * 16;
    float bR[2], bZ[2], bN[2];
    half8 wr[2][8], wz[2][8], wn[2][8];
    #pragma unroll
    for (int nt = 0; nt < 2; nt++) {
      const int j = w*32 + nt*16 + c16;
      bR[nt] = bih1[j]       + bhh1[j];
      bZ[nt] = bih1[256 + j] + bhh1[256 + j];
      bN[nt] = bih1[512 + j];
      const _Float16* WR = wfih1 + (size_t)(2*w + nt)      *4096;
      const _Float16* WZ = wfih1 + (size_t)(16 + 2*w + nt) *4096;
      const _Float16* WN = wfih1 + (size_t)(32 + 2*w + nt) *4096;
      #pragma unroll
      for (int kb = 0; kb < 8; kb++) {
        wr[nt][kb] = *(const half8*)&WR[(kb*64 + l)*8];  PIN_A(wr[nt][kb]);
        wz[nt][kb] = *(const half8*)&WZ[(kb*64 + l)*8];  PIN_A(wz[nt][kb]);
        wn[nt][kb] = *(const half8*)&WN[(kb*64 + l)*8];  PIN_A(wn[nt][kb]);
      }
    }
    // lane l supplies A[row = l&15][k = kb*32 + (l>>4)*8 + 0..7]
    const float* xb = x + (size_t)(b0 + (l & 15))*256 + (l >> 4)*8;

    for (int g = par; g < 32; g += 2) {
      const int t0 = g*16;
      for (int t = t0; t < t0 + 16; t++) {
        const float* xp = xb + (size_t)t*65536;
        f32x4 aR[2], aZ[2], aN[2];
        #pragma unroll
        for (int nt = 0; nt < 2; nt++) {
          aR[nt] = (f32x4){0.f,0.f,0.f,0.f};
          aZ[nt] = (f32x4){0.f,0.f,0.f,0.f};
          aN[nt] = (f32x4){0.f,0.f,0.f,0.f};
        }
        #pragma unroll
        for (int kb = 0; kb < 8; kb++) {
          float4 f0 = *(const float4*)(xp + kb*32);
          float4 f1 = *(const float4*)(xp + kb*32 + 4);
          half8 a;
          a[0] = (_Float16)f0.x; a[1] = (_Float16)f0.y;
          a[2] = (_Float16)f0.z; a[3] = (_Float16)f0.w;
          a[4] = (_Float16)f1.x; a[5] = (_Float16)f1.y;
          a[6] = (_Float16)f1.z; a[7] = (_Float16)f1.w;
          #pragma unroll
          for (int nt = 0; nt < 2; nt++) {
            aR[nt] = MFMA_F16(a, wr[nt][kb], aR[nt], 0, 0, 0);
            aZ[nt] = MFMA_F16(a, wz[nt][kb], aZ[nt], 0, 0, 0);
            aN[nt] = MFMA_F16(a, wn[nt][kb], aN[nt], 0, 0, 0);
          }
        }
        #pragma unroll
        for (int nt = 0; nt < 2; nt++) {
          _Float16* op = gi1 + ((size_t)t*256 + (2*w + nt)*16 + bb)*768 + l*12;
          half4 vR, vZ, vN;
          #pragma unroll
          for (int i = 0; i < 4; i++) {
            vR[i] = (_Float16)(aR[nt][i] + bR[nt]);
            vZ[i] = (_Float16)(aZ[nt][i] + bZ[nt]);
            vN[i] = (_Float16)(aN[nt][i] + bN[nt]);
          }
          *(half4*)(op)     = vR;
          *(half4*)(op + 4) = vZ;
          *(half4*)(op + 8) = vN;
        }
      }
      __syncthreads();                          // drains all waves' stores
      if (tid == 0) ST_REL(&flag0[bb*2 + par], t0 + 16);
    }
    return;
  }

  if (role >= 32) {
    // ------------------- gemm2 producer -------------------
    const int id = role - 32, bb = id >> 1, par = id & 1;
    float bR[2], bZ[2], bN[2];
    half8 wr[2][8], wz[2][8], wn[2][8];
    #pragma unroll
    for (int nt = 0; nt < 2; nt++) {
      const int j = w*32 + nt*16 + c16;
      bR[nt] = bih2[j]       + bhh2[j];
      bZ[nt] = bih2[256 + j] + bhh2[256 + j];
      bN[nt] = bih2[512 + j];
      const _Float16* WR = wfih2 + (size_t)(2*w + nt)      *4096;
      const _Float16* WZ = wfih2 + (size_t)(16 + 2*w + nt) *4096;
      const _Float16* WN = wfih2 + (size_t)(32 + 2*w + nt) *4096;
      #pragma unroll
      for (int kb = 0; kb < 8; kb++) {
        wr[nt][kb] = *(const half8*)&WR[(kb*64 + l)*8];  PIN_A(wr[nt][kb]);
        wz[nt][kb] = *(const half8*)&WZ[(kb*64 + l)*8];  PIN_A(wz[nt][kb]);
        wn[nt][kb] = *(const half8*)&WN[(kb*64 + l)*8];  PIN_A(wn[nt][kb]);
      }
    }

    for (int g = par; g < 32; g += 2) {
      const int t0 = g*16;
      if (tid == 0) {
        while (LD_RLX(&flag1[bb]) < t0 + 16) __builtin_amdgcn_s_sleep(10);
        if (g >= 4)
          while (LD_RLX(&flag3[bb]) < (g - 3)*16) __builtin_amdgcn_s_sleep(10);
        (void)LD_ACQ(&flag1[bb]);               // acquire: invalidate caches
      }
      __syncthreads();
      for (int t = t0; t < t0 + 16; t++) {
        const _Float16* ap = h1seq + (size_t)t*65536 + (size_t)bb*4096 + l*8;
        f32x4 aR[2], aZ[2], aN[2];
        #pragma unroll
        for (int nt = 0; nt < 2; nt++) {
          aR[nt] = (f32x4){0.f,0.f,0.f,0.f};
          aZ[nt] = (f32x4){0.f,0.f,0.f,0.f};
          aN[nt] = (f32x4){0.f,0.f,0.f,0.f};
        }
        #pragma unroll
        for (int kb = 0; kb < 8; kb++) {
          half8 a = *(const half8*)&ap[kb*512];
          #pragma unroll
          for (int nt = 0; nt < 2; nt++) {
            aR[nt] = MFMA_F16(a, wr[nt][kb], aR[nt], 0, 0, 0);
            aZ[nt] = MFMA_F16(a, wz[nt][kb], aZ[nt], 0, 0, 0);
            aN[nt] = MFMA_F16(a, wn[nt][kb], aN[nt], 0, 0, 0);
          }
        }
        #pragma unroll
        for (int nt = 0; nt < 2; nt++) {
          _Float16* op = gi2 + ((size_t)(t & 63)*256 + (2*w + nt)*16 + bb)*768 + l*12;
          half4 vR, vZ, vN;
          #pragma unroll
          for (int i = 0; i < 4; i++) {
            vR[i] = (_Float16)(aR[nt][i] + bR[nt]);
            vZ[i] = (_Float16)(aZ[nt][i] + bZ[nt]);
            vN[i] = (_Float16)(aN[nt][i] + bN[nt]);
          }
          *(half4*)(op)     = vR;
          *(half4*)(op + 4) = vZ;
          *(half4*)(op + 8) = vN;
        }
      }
      __syncthreads();                          // drains all waves' stores
      if (tid == 0) ST_REL(&flag2[bb*2 + par], t0 + 16);
    }
    return;
  }

  // ------------------- GRU roles -------------------
  const bool L1 = (role < 16);
  const int bb = L1 ? role : role - 16;
  const int b0 = bb * 16;
  const _Float16* gi = L1 ? gi1 : gi2;
  const _Float16* Wf = L1 ? wfhh1 : wfhh2;
  const float* bhh   = L1 ? bhh1 : bhh2;
  float* hcarry      = L1 ? hc1 : hc2;

  { // stage initial h (f32 carry -> fp16 frags), 8 halves per thread
    int n = tid*8;
    int b = n >> 8, k = n & 255;
    const float4* s4 = (const float4*)&hcarry[(size_t)(b0 + b)*256 + k];
    float4 v0 = s4[0], v1 = s4[1];
    half8 hv;
    hv[0] = (_Float16)v0.x; hv[1] = (_Float16)v0.y;
    hv[2] = (_Float16)v0.z; hv[3] = (_Float16)v0.w;
    hv[4] = (_Float16)v1.x; hv[5] = (_Float16)v1.y;
    hv[6] = (_Float16)v1.z; hv[7] = (_Float16)v1.w;
    *(half8*)&hl[0][(k >> 5)*512 + (((k >> 3) & 3)*16 + b)*8] = hv;
  }

  float bN[2];
  float hprev[2][4];
  half8 wr[2][8], wz[2][8], wn[2][6];           // wn holds kb=2..7
  int   wr_off[2];
  int   gil[2];
  #pragma unroll
  for (int nt = 0; nt < 2; nt++) {
    const int j = w*32 + nt*16 + c16;
    bN[nt] = bhh[512 + j];
    #pragma unroll
    for (int i = 0; i < 4; i++)
      hprev[nt][i] = hcarry[(size_t)(b0 + q*4 + i)*256 + j];
    const _Float16* WR = Wf + (size_t)(2*w + nt)      *4096;
    const _Float16* WZ = Wf + (size_t)(16 + 2*w + nt) *4096;
    const _Float16* WN = Wf + (size_t)(32 + 2*w + nt) *4096;
    #pragma unroll
    for (int kb = 0; kb < 8; kb++) {
      wr[nt][kb] = *(const half8*)&WR[(kb*64 + l)*8];  PIN_A(wr[nt][kb]);
      wz[nt][kb] = *(const half8*)&WZ[(kb*64 + l)*8];  PIN_A(wz[nt][kb]);
    }
    #pragma unroll
    for (int kb = 2; kb < 8; kb++) {
      wn[nt][kb-2] = *(const half8*)&WN[(kb*64 + l)*8];  PIN_A(wn[nt][kb-2]);
    }
    #pragma unroll
    for (int kb = 0; kb < 2; kb++)
      *(half8*)&wn_l[((w*2 + nt)*2 + kb)*512 + l*8] =
          *(const half8*)&WN[(kb*64 + l)*8];
    wr_off[nt] = (j >> 5)*512 + ((j >> 3) & 3)*128 + (j & 7);
    gil[nt]    = ((2*w + nt)*16 + bb)*768 + l*12;
  }
  _Float16* hq = L1 ? (h1seq + (size_t)bb*4096 + tid*8) : (_Float16*)nullptr;

  __syncthreads();
  half4 pR[2], pZ[2], pN[2];                    // gi prefetch registers
  int cur = 0;
  for (int t = 0; t < 512; t++) {
    if ((t & 15) == 0) {                        // acquire gi group
      if (tid == 0) {
        int* f = L1 ? &flag0[bb*2 + ((t >> 4) & 1)]
                    : &flag2[bb*2 + ((t >> 4) & 1)];
        while (LD_RLX(f) < t + 16) __builtin_amdgcn_s_sleep(10);
        (void)LD_ACQ(f);
      }
      __syncthreads();
      const int tm = L1 ? t : (t & 63);
      const _Float16* gbase = gi + (size_t)tm*196608;
      #pragma unroll
      for (int nt = 0; nt < 2; nt++) {
        const _Float16* gp = gbase + gil[nt];
        pR[nt] = *(const half4*)(gp);
        pZ[nt] = *(const half4*)(gp + 4);
        pN[nt] = *(const half4*)(gp + 8);
      }
    }
    half4 vR[2], vZ[2], vN[2];
    #pragma unroll
    for (int nt = 0; nt < 2; nt++) {
      vR[nt] = pR[nt]; vZ[nt] = pZ[nt]; vN[nt] = pN[nt];
    }

    f32x4 aR[2], aZ[2], aN[2];
    #pragma unroll
    for (int nt = 0; nt < 2; nt++) {
      aR[nt] = (f32x4){0.f,0.f,0.f,0.f};
      aZ[nt] = (f32x4){0.f,0.f,0.f,0.f};
      aN[nt] = (f32x4){0.f,0.f,0.f,0.f};
    }
    #pragma unroll
    for (int kb = 0; kb < 8; kb++) {
      half8 a = *(const half8*)&hl[cur][kb*512 + l*8];
      #pragma unroll
      for (int nt = 0; nt < 2; nt++) {
        half8 bn = (kb < 2)
            ? *(const half8*)&wn_l[((w*2 + nt)*2 + kb)*512 + l*8]
            : wn[nt][kb-2];
        aR[nt] = MFMA_F16(a, wr[nt][kb], aR[nt], 0, 0, 0);
        aZ[nt] = MFMA_F16(a, wz[nt][kb], aZ[nt], 0, 0, 0);
        aN[nt] = MFMA_F16(a, bn,         aN[nt], 0, 0, 0);
      }
    }

    // prefetch gi(t+1) while MFMAs retire (same published group only)
    if (((t + 1) & 15) != 0) {
      const int tn = L1 ? (t + 1) : ((t + 1) & 63);
      const _Float16* gbase = gi + (size_t)tn*196608;
      #pragma unroll
      for (int nt = 0; nt < 2; nt++) {
        const _Float16* gp = gbase + gil[nt];
        pR[nt] = *(const half4*)(gp);
        pZ[nt] = *(const half4*)(gp + 4);
        pN[nt] = *(const half4*)(gp + 8);
      }
    }

    const int nxt = cur ^ 1;
    #pragma unroll
    for (int nt = 0; nt < 2; nt++) {
      #pragma unroll
      for (int i = 0; i < 4; i++) {
        float r  = sigm_f(aR[nt][i] + (float)vR[nt][i]);
        float z  = sigm_f(aZ[nt][i] + (float)vZ[nt][i]);
        float nn = tanh_fast((float)vN[nt][i] + r*(aN[nt][i] + bN[nt]));
        float hp = nn + z*(hprev[nt][i] - nn);  // (1-z)*n + z*h
        hprev[nt][i] = hp;
        hl[nxt][wr_off[nt] + (q*4 + i)*8] = (_Float16)hp;
      }
    }

    if ((t & 15) == 0 && t > 0) {
      bar_strong();                             // drains hq stores <= t-1
      if (tid == 0) {
        if (L1) ST_REL(&flag1[bb], t);          // steps 0..t-1 published
        else    ST_REL(&flag3[bb], t);          // steps 0..t-1 consumed
      }
    } else {
      bar_weak();                               // LDS visibility only
    }
    if (L1)
      *(half8*)&hq[(size_t)t*65536] = *(const half8*)&hl[nxt][tid*8];
    cur = nxt;
  }
  bar_strong();                                 // drain hq(511)
  if (tid == 0) {
    if (L1) ST_REL(&flag1[bb], 512);
    else    ST_REL(&flag3[bb], 512);
  }

  #pragma unroll
  for (int nt = 0; nt < 2; nt++) {
    const int j = w*32 + nt*16 + c16;
    #pragma unroll
    for (int i = 0; i < 4; i++)
      hcarry[(size_t)(b0 + q*4 + i)*256 + j] = hprev[nt][i];
  }
}

// ---------------------------------------------------------------------------
extern "C" void kernel_launch(void* const* d_in, const int* in_sizes, int n_in,
                              void* d_out, int out_size, void* d_ws, size_t ws_size,
                              hipStream_t stream)
{
  const float* x     = (const float*)d_in[0];
  const float* h1_0  = (const float*)d_in[1];
  const float* h2_0  = (const float*)d_in[2];
  const float* w_ih1 = (const float*)d_in[3];
  const float* w_hh1 = (const float*)d_in[4];
  const float* b_ih1 = (const float*)d_in[5];
  const float* b_hh1 = (const float*)d_in[6];
  const float* w_ih2 = (const float*)d_in[7];
  const float* w_hh2 = (const float*)d_in[8];
  const float* b_ih2 = (const float*)d_in[9];
  const float* b_hh2 = (const float*)d_in[10];

  char* ws = (char*)d_ws;
  size_t off = 0;
  auto alloc = [&](size_t bytes) -> void* {
    void* p = ws + off; off += (bytes + 255) & ~(size_t)255; return p;
  };
  int*      slots   = (int*)     alloc(16);
  _Float16* wf_ih1  = (_Float16*)alloc(196608*2);
  _Float16* wf_hh1  = (_Float16*)alloc(196608*2);
  _Float16* wf_ih2  = (_Float16*)alloc(196608*2);
  _Float16* wf_hh2  = (_Float16*)alloc(196608*2);
  float*    hc1     = (float*)   alloc(256*256*4);
  float*    hc2     = (float*)   alloc(256*256*4);
  int*      flag0   = (int*)     alloc(32*4);
  int*      flag1   = (int*)     alloc(16*4);
  int*      flag2   = (int*)     alloc(32*4);
  int*      flag3   = (int*)     alloc(16*4);
  _Float16* gi1     = (_Float16*)alloc((size_t)512*393216);   // 201 MB
  _Float16* h1seq   = (_Float16*)alloc((size_t)512*131072);   //  67 MB
  _Float16* gi2     = (_Float16*)alloc((size_t)64*393216);    //  25 MB ring

  k_maxabs<<<128, 256, 0, stream>>>(w_ih1, w_hh1, w_ih2, w_hh2, 196608, slots);
  k_quant <<<3072, 256, 0, stream>>>(w_ih1, w_hh1, w_ih2, w_hh2, slots,
                                     wf_ih1, wf_hh1, wf_ih2, wf_hh2);
  (void)hipMemcpyAsync(hc1, h1_0, 256*256*4, hipMemcpyDeviceToDevice, stream);
  (void)hipMemcpyAsync(hc2, h2_0, 256*256*4, hipMemcpyDeviceToDevice, stream);

  k_pipe<<<96, 512, 0, stream>>>(x, wf_ih1, b_ih1, gi1, wf_hh1, b_hh1,
                                 hc1, h1seq, wf_ih2, b_ih2, b_hh2, wf_hh2,
                                 hc2, gi2, flag0, flag1, flag2, flag3);

  (void)hipMemcpyAsync(d_out, hc2, 256*256*4, hipMemcpyDeviceToDevice, stream);
}

// Round 5
// 1340.775 us; speedup vs baseline: 1.6217x; 1.6217x over previous
//
#include <hip/hip_runtime.h>
#include <hip/hip_fp16.h>
#include <cstdint>

typedef _Float16 half8 __attribute__((ext_vector_type(8)));
typedef _Float16 half4 __attribute__((ext_vector_type(4)));
typedef float f32x4 __attribute__((ext_vector_type(4)));

#define MFMA_F16 __builtin_amdgcn_mfma_f32_16x16x32_f16
#define PIN(x)   asm volatile("" : "+v"(x))
#define LD_RLX(p)   __hip_atomic_load((p),  __ATOMIC_RELAXED, __HIP_MEMORY_SCOPE_AGENT)
#define LD_ACQ(p)   __hip_atomic_load((p),  __ATOMIC_ACQUIRE, __HIP_MEMORY_SCOPE_AGENT)
#define ST_REL(p,v) __hip_atomic_store((p),(v), __ATOMIC_RELEASE, __HIP_MEMORY_SCOPE_AGENT)

__device__ __forceinline__ float fast_rcp(float x){
#if __has_builtin(__builtin_amdgcn_rcpf)
  return __builtin_amdgcn_rcpf(x);
#else
  return 1.0f/x;
#endif
}
__device__ __forceinline__ float fast_exp2(float x){
#if __has_builtin(__builtin_amdgcn_exp2f)
  return __builtin_amdgcn_exp2f(x);
#else
  return exp2f(x);
#endif
}
__device__ __forceinline__ float sigm_f(float x){
  return fast_rcp(1.0f + fast_exp2(-1.44269504f*x));
}
__device__ __forceinline__ float tanh_fast(float x){
  float e = fast_exp2(-2.88539008f*x);            // e^(-2x)
  return fmaf(2.0f, fast_rcp(1.0f + e), -1.0f);   // 2/(1+e) - 1
}

// Weak barrier: LDS visibility only (no vmcnt drain -> global stores/loads
// stay in flight across steps). Strong barrier: full drain, used only at
// 16-step flag boundaries (cross-block release/acquire protocol unchanged).
__device__ __forceinline__ void bar_weak(){
  asm volatile("s_waitcnt lgkmcnt(0)" ::: "memory");
  __builtin_amdgcn_s_barrier();
  asm volatile("" ::: "memory");
}
__device__ __forceinline__ void bar_strong(){
  asm volatile("s_waitcnt vmcnt(0) lgkmcnt(0)" ::: "memory");
  __builtin_amdgcn_s_barrier();
  asm volatile("" ::: "memory");
}

// ---------------------------------------------------------------------------
// Phase A1: per-matrix max|w| (4 matrices of 768x256)
// ---------------------------------------------------------------------------
__global__ __launch_bounds__(256) void k_maxabs(
    const float* __restrict__ w0, const float* __restrict__ w1,
    const float* __restrict__ w2, const float* __restrict__ w3,
    int n, int* __restrict__ slots)
{
  const float* srcs[4] = {w0, w1, w2, w3};
  int m    = blockIdx.x >> 5;
  int part = blockIdx.x & 31;
  const float* w = srcs[m];
  float loc = 0.0f;
  for (int i = part*256 + threadIdx.x; i < n; i += 32*256)
    loc = fmaxf(loc, fabsf(w[i]));
  for (int off = 32; off; off >>= 1)
    loc = fmaxf(loc, __shfl_down(loc, off, 64));
  __shared__ float red[4];
  int wv = threadIdx.x >> 6;
  if ((threadIdx.x & 63) == 0) red[wv] = loc;
  __syncthreads();
  if (threadIdx.x == 0) {
    float mx = fmaxf(fmaxf(red[0], red[1]), fmaxf(red[2], red[3]));
    atomicMax(&slots[m], __float_as_int(mx));
  }
}

// ---------------------------------------------------------------------------
// Phase A2: fake-quantize -> fp16, MFMA-B-fragment-swizzled layout.
// ---------------------------------------------------------------------------
__global__ __launch_bounds__(256) void k_quant(
    const float* __restrict__ w0, const float* __restrict__ w1,
    const float* __restrict__ w2, const float* __restrict__ w3,
    const int* __restrict__ slots,
    _Float16* __restrict__ f0, _Float16* __restrict__ f1,
    _Float16* __restrict__ f2, _Float16* __restrict__ f3)
{
  const float* srcs[4] = {w0, w1, w2, w3};
  _Float16*    dsts[4] = {f0, f1, f2, f3};
  int idx = blockIdx.x*256 + threadIdx.x;
  int m = idx / 196608;
  int e = idx - m*196608;
  float scale = __int_as_float(slots[m]) * (1.0f/127.0f);
  float w = srcs[m][e];
  float q = rintf(w/scale) * scale;
  int g = e >> 8, k = e & 255;
  int tile = g >> 4, kb = k >> 5;
  int lane = ((k >> 3) & 3)*16 + (g & 15);
  int off  = (tile*8 + kb)*512 + lane*8 + (k & 7);
  dsts[m][off] = (_Float16)q;
}

// ---------------------------------------------------------------------------
// Phase A3: x f32 -> fp16 in h1seq-style MFMA A-fragment layout.
// xh[t*65536 + bb*4096 + kb*512 + lane*8 + j] where lane=(k8&3)*16+row,
// kb=k8>>2 — identical addressing to the gemm2 producer's h1seq reads.
// ---------------------------------------------------------------------------
__global__ __launch_bounds__(256) void k_xcast(
    const float* __restrict__ x, _Float16* __restrict__ xh)
{
  int n = blockIdx.x*256 + threadIdx.x;          // 4,194,304 total
  int t   = n >> 13;
  int rem = n & 8191;
  int bg  = rem >> 5;                            // batch row 0..255
  int k8  = rem & 31;                            // k octet 0..31
  const float4* src = (const float4*)&x[((size_t)t*256 + bg)*256 + k8*8];
  float4 v0 = src[0], v1 = src[1];
  half8 hv;
  hv[0] = (_Float16)v0.x; hv[1] = (_Float16)v0.y;
  hv[2] = (_Float16)v0.z; hv[3] = (_Float16)v0.w;
  hv[4] = (_Float16)v1.x; hv[5] = (_Float16)v1.y;
  hv[6] = (_Float16)v1.z; hv[7] = (_Float16)v1.w;
  int bb = bg >> 4, b = bg & 15, kb = k8 >> 2, lane = (k8 & 3)*16 + b;
  *(half8*)&xh[(size_t)t*65536 + (size_t)bb*4096 + kb*512 + lane*8] = hv;
}

// ---------------------------------------------------------------------------
// Fully fused pipeline: 96 blocks x 512 thr (8 waves).
//   role 0..15  : layer-1 GRU. Acquires gi1 groups via flag0,
//                 publishes h1seq progress via flag1.
//   role 16..31 : layer-2 GRU. Acquires gi2 via flag2, publishes flag3.
//   role 32..63 : gemm2 producers: h1seq @ W_ih2^T -> gi2 ring (64-step).
//   role 64..95 : gemm1 producers: xh @ W_ih1^T -> gi1 (full buffer).
// gemm1 producers now read pre-cast fp16 xh (no f32 loads, no cvts) and
// never wait — their step cost must stay under 2x the consumer pace so
// flag0 waits vanish (R2/R3's regression was producer-limited pace p1/2).
// ---------------------------------------------------------------------------
__global__ __launch_bounds__(512, 1) void k_pipe(
    const _Float16* __restrict__ xh,
    const _Float16* __restrict__ wfih1, const float* __restrict__ bih1,
    _Float16* __restrict__ gi1, const _Float16* __restrict__ wfhh1,
    const float* __restrict__ bhh1, float* __restrict__ hc1,
    _Float16* __restrict__ h1seq,
    const _Float16* __restrict__ wfih2, const float* __restrict__ bih2,
    const float* __restrict__ bhh2, const _Float16* __restrict__ wfhh2,
    float* __restrict__ hc2, _Float16* __restrict__ gi2,
    int* __restrict__ flag0, int* __restrict__ flag1,
    int* __restrict__ flag2, int* __restrict__ flag3)
{
  __shared__ __align__(16) _Float16 hl[2][4096];   // 16 KB h dbuf (GRU roles)
  __shared__ __align__(16) _Float16 wn_l[16384];   // 32 KB: [w][nt][kb<2][512]
  const int role = blockIdx.x;
  const int tid  = threadIdx.x;
  const int w = tid >> 6, l = tid & 63, q = l >> 4, c16 = l & 15;

  if (role >= 32) {
    // ------------- gemm producers (gemm1: roles 64..95, gemm2: 32..63) -----
    const bool G1 = (role >= 64);
    const int id = G1 ? role - 64 : role - 32;
    const int bb = id >> 1, par = id & 1;
    const _Float16* Wsrc = G1 ? wfih1 : wfih2;
    const float*    bihp = G1 ? bih1  : bih2;
    const float*    bhhp = G1 ? bhh1  : bhh2;
    const _Float16* Asrc = G1 ? xh    : h1seq;
    _Float16*       gout = G1 ? gi1   : gi2;

    float bR[2], bZ[2], bN[2];
    half8 wr[2][8], wz[2][8], wn[2][8];
    #pragma unroll
    for (int nt = 0; nt < 2; nt++) {
      const int j = w*32 + nt*16 + c16;
      bR[nt] = bihp[j]       + bhhp[j];
      bZ[nt] = bihp[256 + j] + bhhp[256 + j];
      bN[nt] = bihp[512 + j];
      const _Float16* WR = Wsrc + (size_t)(2*w + nt)      *4096;
      const _Float16* WZ = Wsrc + (size_t)(16 + 2*w + nt) *4096;
      const _Float16* WN = Wsrc + (size_t)(32 + 2*w + nt) *4096;
      #pragma unroll
      for (int kb = 0; kb < 8; kb++) {
        wr[nt][kb] = *(const half8*)&WR[(kb*64 + l)*8];  PIN(wr[nt][kb]);
        wz[nt][kb] = *(const half8*)&WZ[(kb*64 + l)*8];  PIN(wz[nt][kb]);
        wn[nt][kb] = *(const half8*)&WN[(kb*64 + l)*8];  PIN(wn[nt][kb]);
      }
    }

    for (int g = par; g < 32; g += 2) {
      const int t0 = g*16;
      if (!G1) {
        if (tid == 0) {
          while (LD_RLX(&flag1[bb]) < t0 + 16) __builtin_amdgcn_s_sleep(10);
          if (g >= 4)
            while (LD_RLX(&flag3[bb]) < (g - 3)*16) __builtin_amdgcn_s_sleep(10);
          (void)LD_ACQ(&flag1[bb]);             // acquire: invalidate caches
        }
        __syncthreads();
      }
      for (int t = t0; t < t0 + 16; t++) {
        const _Float16* ap = Asrc + (size_t)t*65536 + (size_t)bb*4096 + l*8;
        f32x4 aR[2], aZ[2], aN[2];
        #pragma unroll
        for (int nt = 0; nt < 2; nt++) {
          aR[nt] = (f32x4){0.f,0.f,0.f,0.f};
          aZ[nt] = (f32x4){0.f,0.f,0.f,0.f};
          aN[nt] = (f32x4){0.f,0.f,0.f,0.f};
        }
        #pragma unroll
        for (int kb = 0; kb < 8; kb++) {
          half8 a = *(const half8*)&ap[kb*512];
          #pragma unroll
          for (int nt = 0; nt < 2; nt++) {
            aR[nt] = MFMA_F16(a, wr[nt][kb], aR[nt], 0, 0, 0);
            aZ[nt] = MFMA_F16(a, wz[nt][kb], aZ[nt], 0, 0, 0);
            aN[nt] = MFMA_F16(a, wn[nt][kb], aN[nt], 0, 0, 0);
          }
        }
        const size_t trow = G1 ? (size_t)t : (size_t)(t & 63);
        #pragma unroll
        for (int nt = 0; nt < 2; nt++) {
          _Float16* op = gout + (trow*256 + (2*w + nt)*16 + bb)*768 + l*12;
          half4 vR, vZ, vN;
          #pragma unroll
          for (int i = 0; i < 4; i++) {
            vR[i] = (_Float16)(aR[nt][i] + bR[nt]);
            vZ[i] = (_Float16)(aZ[nt][i] + bZ[nt]);
            vN[i] = (_Float16)(aN[nt][i] + bN[nt]);
          }
          *(half4*)(op)     = vR;
          *(half4*)(op + 4) = vZ;
          *(half4*)(op + 8) = vN;
        }
      }
      __syncthreads();                          // drains all waves' stores
      if (tid == 0) {
        if (G1) ST_REL(&flag0[bb*2 + par], t0 + 16);
        else    ST_REL(&flag2[bb*2 + par], t0 + 16);
      }
    }
    return;
  }

  // ------------------- GRU roles -------------------
  const bool L1 = (role < 16);
  const int bb = L1 ? role : role - 16;
  const int b0 = bb * 16;
  const _Float16* gi = L1 ? gi1 : gi2;
  const _Float16* Wf = L1 ? wfhh1 : wfhh2;
  const float* bhh   = L1 ? bhh1 : bhh2;
  float* hcarry      = L1 ? hc1 : hc2;

  { // stage initial h (f32 carry -> fp16 frags), 8 halves per thread
    int n = tid*8;
    int b = n >> 8, k = n & 255;
    const float4* s4 = (const float4*)&hcarry[(size_t)(b0 + b)*256 + k];
    float4 v0 = s4[0], v1 = s4[1];
    half8 hv;
    hv[0] = (_Float16)v0.x; hv[1] = (_Float16)v0.y;
    hv[2] = (_Float16)v0.z; hv[3] = (_Float16)v0.w;
    hv[4] = (_Float16)v1.x; hv[5] = (_Float16)v1.y;
    hv[6] = (_Float16)v1.z; hv[7] = (_Float16)v1.w;
    *(half8*)&hl[0][(k >> 5)*512 + (((k >> 3) & 3)*16 + b)*8] = hv;
  }

  float bN[2];
  float hprev[2][4];
  half8 wr[2][8], wz[2][8], wn[2][6];           // wn holds kb=2..7
  int   wr_off[2];
  int   gil[2];
  #pragma unroll
  for (int nt = 0; nt < 2; nt++) {
    const int j = w*32 + nt*16 + c16;
    bN[nt] = bhh[512 + j];
    #pragma unroll
    for (int i = 0; i < 4; i++)
      hprev[nt][i] = hcarry[(size_t)(b0 + q*4 + i)*256 + j];
    const _Float16* WR = Wf + (size_t)(2*w + nt)      *4096;
    const _Float16* WZ = Wf + (size_t)(16 + 2*w + nt) *4096;
    const _Float16* WN = Wf + (size_t)(32 + 2*w + nt) *4096;
    #pragma unroll
    for (int kb = 0; kb < 8; kb++) {
      wr[nt][kb] = *(const half8*)&WR[(kb*64 + l)*8];  PIN(wr[nt][kb]);
      wz[nt][kb] = *(const half8*)&WZ[(kb*64 + l)*8];  PIN(wz[nt][kb]);
    }
    #pragma unroll
    for (int kb = 2; kb < 8; kb++) {
      wn[nt][kb-2] = *(const half8*)&WN[(kb*64 + l)*8];  PIN(wn[nt][kb-2]);
    }
    #pragma unroll
    for (int kb = 0; kb < 2; kb++)
      *(half8*)&wn_l[((w*2 + nt)*2 + kb)*512 + l*8] =
          *(const half8*)&WN[(kb*64 + l)*8];
    wr_off[nt] = (j >> 5)*512 + ((j >> 3) & 3)*128 + (j & 7);
    gil[nt]    = ((2*w + nt)*16 + bb)*768 + l*12;
  }
  _Float16* hq = L1 ? (h1seq + (size_t)bb*4096 + tid*8) : (_Float16*)nullptr;

  __syncthreads();
  half4 pR[2], pZ[2], pN[2];                    // gi prefetch registers
  int cur = 0;
  for (int t = 0; t < 512; t++) {
    if ((t & 15) == 0) {                        // acquire gi group
      if (tid == 0) {
        int* f = L1 ? &flag0[bb*2 + ((t >> 4) & 1)]
                    : &flag2[bb*2 + ((t >> 4) & 1)];
        while (LD_RLX(f) < t + 16) __builtin_amdgcn_s_sleep(10);
        (void)LD_ACQ(f);
      }
      __syncthreads();
      const int tm = L1 ? t : (t & 63);
      const _Float16* gbase = gi + (size_t)tm*196608;
      #pragma unroll
      for (int nt = 0; nt < 2; nt++) {
        const _Float16* gp = gbase + gil[nt];
        pR[nt] = *(const half4*)(gp);
        pZ[nt] = *(const half4*)(gp + 4);
        pN[nt] = *(const half4*)(gp + 8);
      }
    }
    half4 vR[2], vZ[2], vN[2];
    #pragma unroll
    for (int nt = 0; nt < 2; nt++) {
      vR[nt] = pR[nt]; vZ[nt] = pZ[nt]; vN[nt] = pN[nt];
    }

    f32x4 aR[2], aZ[2], aN[2];
    #pragma unroll
    for (int nt = 0; nt < 2; nt++) {
      aR[nt] = (f32x4){0.f,0.f,0.f,0.f};
      aZ[nt] = (f32x4){0.f,0.f,0.f,0.f};
      aN[nt] = (f32x4){0.f,0.f,0.f,0.f};
    }
    #pragma unroll
    for (int kb = 0; kb < 8; kb++) {
      half8 a = *(const half8*)&hl[cur][kb*512 + l*8];
      #pragma unroll
      for (int nt = 0; nt < 2; nt++) {
        half8 bn = (kb < 2)
            ? *(const half8*)&wn_l[((w*2 + nt)*2 + kb)*512 + l*8]
            : wn[nt][kb-2];
        aR[nt] = MFMA_F16(a, wr[nt][kb], aR[nt], 0, 0, 0);
        aZ[nt] = MFMA_F16(a, wz[nt][kb], aZ[nt], 0, 0, 0);
        aN[nt] = MFMA_F16(a, bn,         aN[nt], 0, 0, 0);
      }
    }

    // prefetch gi(t+1) while MFMAs retire (same published group only)
    if (((t + 1) & 15) != 0) {
      const int tn = L1 ? (t + 1) : ((t + 1) & 63);
      const _Float16* gbase = gi + (size_t)tn*196608;
      #pragma unroll
      for (int nt = 0; nt < 2; nt++) {
        const _Float16* gp = gbase + gil[nt];
        pR[nt] = *(const half4*)(gp);
        pZ[nt] = *(const half4*)(gp + 4);
        pN[nt] = *(const half4*)(gp + 8);
      }
    }

    const int nxt = cur ^ 1;
    #pragma unroll
    for (int nt = 0; nt < 2; nt++) {
      #pragma unroll
      for (int i = 0; i < 4; i++) {
        float r  = sigm_f(aR[nt][i] + (float)vR[nt][i]);
        float z  = sigm_f(aZ[nt][i] + (float)vZ[nt][i]);
        float nn = tanh_fast((float)vN[nt][i] + r*(aN[nt][i] + bN[nt]));
        float hp = nn + z*(hprev[nt][i] - nn);  // (1-z)*n + z*h
        hprev[nt][i] = hp;
        hl[nxt][wr_off[nt] + (q*4 + i)*8] = (_Float16)hp;
      }
    }

    if ((t & 15) == 0 && t > 0) {
      bar_strong();                             // drains hq stores <= t-1
      if (tid == 0) {
        if (L1) ST_REL(&flag1[bb], t);          // steps 0..t-1 published
        else    ST_REL(&flag3[bb], t);          // steps 0..t-1 consumed
      }
    } else {
      bar_weak();                               // LDS visibility only
    }
    if (L1)
      *(half8*)&hq[(size_t)t*65536] = *(const half8*)&hl[nxt][tid*8];
    cur = nxt;
  }
  bar_strong();                                 // drain hq(511)
  if (tid == 0) {
    if (L1) ST_REL(&flag1[bb], 512);
    else    ST_REL(&flag3[bb], 512);
  }

  #pragma unroll
  for (int nt = 0; nt < 2; nt++) {
    const int j = w*32 + nt*16 + c16;
    #pragma unroll
    for (int i = 0; i < 4; i++)
      hcarry[(size_t)(b0 + q*4 + i)*256 + j] = hprev[nt][i];
  }
}

// ---------------------------------------------------------------------------
extern "C" void kernel_launch(void* const* d_in, const int* in_sizes, int n_in,
                              void* d_out, int out_size, void* d_ws, size_t ws_size,
                              hipStream_t stream)
{
  const float* x     = (const float*)d_in[0];
  const float* h1_0  = (const float*)d_in[1];
  const float* h2_0  = (const float*)d_in[2];
  const float* w_ih1 = (const float*)d_in[3];
  const float* w_hh1 = (const float*)d_in[4];
  const float* b_ih1 = (const float*)d_in[5];
  const float* b_hh1 = (const float*)d_in[6];
  const float* w_ih2 = (const float*)d_in[7];
  const float* w_hh2 = (const float*)d_in[8];
  const float* b_ih2 = (const float*)d_in[9];
  const float* b_hh2 = (const float*)d_in[10];

  char* ws = (char*)d_ws;
  size_t off = 0;
  auto alloc = [&](size_t bytes) -> void* {
    void* p = ws + off; off += (bytes + 255) & ~(size_t)255; return p;
  };
  int*      slots   = (int*)     alloc(16);
  _Float16* wf_ih1  = (_Float16*)alloc(196608*2);
  _Float16* wf_hh1  = (_Float16*)alloc(196608*2);
  _Float16* wf_ih2  = (_Float16*)alloc(196608*2);
  _Float16* wf_hh2  = (_Float16*)alloc(196608*2);
  float*    hc1     = (float*)   alloc(256*256*4);
  float*    hc2     = (float*)   alloc(256*256*4);
  int*      flag0   = (int*)     alloc(32*4);
  int*      flag1   = (int*)     alloc(16*4);
  int*      flag2   = (int*)     alloc(32*4);
  int*      flag3   = (int*)     alloc(16*4);
  _Float16* gi1     = (_Float16*)alloc((size_t)512*393216);   // 201 MB
  _Float16* h1seq   = (_Float16*)alloc((size_t)512*131072);   //  67 MB
  _Float16* gi2     = (_Float16*)alloc((size_t)64*393216);    //  25 MB ring
  _Float16* xhbuf   = (_Float16*)alloc((size_t)512*131072);   //  67 MB

  k_maxabs<<<128, 256, 0, stream>>>(w_ih1, w_hh1, w_ih2, w_hh2, 196608, slots);
  k_quant <<<3072, 256, 0, stream>>>(w_ih1, w_hh1, w_ih2, w_hh2, slots,
                                     wf_ih1, wf_hh1, wf_ih2, wf_hh2);
  k_xcast <<<16384, 256, 0, stream>>>(x, xhbuf);
  (void)hipMemcpyAsync(hc1, h1_0, 256*256*4, hipMemcpyDeviceToDevice, stream);
  (void)hipMemcpyAsync(hc2, h2_0, 256*256*4, hipMemcpyDeviceToDevice, stream);

  k_pipe<<<96, 512, 0, stream>>>(xhbuf, wf_ih1, b_ih1, gi1, wf_hh1, b_hh1,
                                 hc1, h1seq, wf_ih2, b_ih2, b_hh2, wf_hh2,
                                 hc2, gi2, flag0, flag1, flag2, flag3);

  (void)hipMemcpyAsync(d_out, hc2, 256*256*4, hipMemcpyDeviceToDevice, stream);
}

// Round 7
// 1338.903 us; speedup vs baseline: 1.6239x; 1.0014x over previous
//
#include <hip/hip_runtime.h>
#include <hip/hip_fp16.h>
#include <cstdint>

typedef _Float16 half8 __attribute__((ext_vector_type(8)));
typedef _Float16 half4 __attribute__((ext_vector_type(4)));
typedef float f32x4 __attribute__((ext_vector_type(4)));

#define MFMA_F16 __builtin_amdgcn_mfma_f32_16x16x32_f16
#define PIN(x)   asm volatile("" : "+v"(x))
// Volatile fragment load: cannot be rematerialized/sunk into the step loop,
// so the register allocator MUST keep the value live in VGPRs for the whole
// kernel (cap 256 via launch_bounds(512,2): 8-wave block, 2 waves/SIMD).
// Plain loads were being re-issued from L2 every step once the compiler
// settled on a 128-reg budget — the hidden ~3000 cy/step cost behind
// VGPR_Count==128 in R1..R5.
#define LDV(p) (*(const volatile half8*)(p))
#define LD_RLX(p)   __hip_atomic_load((p),  __ATOMIC_RELAXED, __HIP_MEMORY_SCOPE_AGENT)
#define LD_ACQ(p)   __hip_atomic_load((p),  __ATOMIC_ACQUIRE, __HIP_MEMORY_SCOPE_AGENT)
#define ST_REL(p,v) __hip_atomic_store((p),(v), __ATOMIC_RELEASE, __HIP_MEMORY_SCOPE_AGENT)

__device__ __forceinline__ float fast_rcp(float x){
#if __has_builtin(__builtin_amdgcn_rcpf)
  return __builtin_amdgcn_rcpf(x);
#else
  return 1.0f/x;
#endif
}
__device__ __forceinline__ float fast_exp2(float x){
#if __has_builtin(__builtin_amdgcn_exp2f)
  return __builtin_amdgcn_exp2f(x);
#else
  return exp2f(x);
#endif
}
__device__ __forceinline__ float sigm_f(float x){
  return fast_rcp(1.0f + fast_exp2(-1.44269504f*x));
}
__device__ __forceinline__ float tanh_fast(float x){
  float e = fast_exp2(-2.88539008f*x);            // e^(-2x)
  return fmaf(2.0f, fast_rcp(1.0f + e), -1.0f);   // 2/(1+e) - 1
}

// Weak barrier: LDS visibility only (no vmcnt drain -> global stores/loads
// stay in flight across steps). Strong barrier: full drain, used only at
// 16-step flag boundaries (cross-block release/acquire protocol unchanged).
__device__ __forceinline__ void bar_weak(){
  asm volatile("s_waitcnt lgkmcnt(0)" ::: "memory");
  __builtin_amdgcn_s_barrier();
  asm volatile("" ::: "memory");
}
__device__ __forceinline__ void bar_strong(){
  asm volatile("s_waitcnt vmcnt(0) lgkmcnt(0)" ::: "memory");
  __builtin_amdgcn_s_barrier();
  asm volatile("" ::: "memory");
}

// ---------------------------------------------------------------------------
// Phase A1: per-matrix max|w| (4 matrices of 768x256)
// ---------------------------------------------------------------------------
__global__ __launch_bounds__(256) void k_maxabs(
    const float* __restrict__ w0, const float* __restrict__ w1,
    const float* __restrict__ w2, const float* __restrict__ w3,
    int n, int* __restrict__ slots)
{
  const float* srcs[4] = {w0, w1, w2, w3};
  int m    = blockIdx.x >> 5;
  int part = blockIdx.x & 31;
  const float* w = srcs[m];
  float loc = 0.0f;
  for (int i = part*256 + threadIdx.x; i < n; i += 32*256)
    loc = fmaxf(loc, fabsf(w[i]));
  for (int off = 32; off; off >>= 1)
    loc = fmaxf(loc, __shfl_down(loc, off, 64));
  __shared__ float red[4];
  int wv = threadIdx.x >> 6;
  if ((threadIdx.x & 63) == 0) red[wv] = loc;
  __syncthreads();
  if (threadIdx.x == 0) {
    float mx = fmaxf(fmaxf(red[0], red[1]), fmaxf(red[2], red[3]));
    atomicMax(&slots[m], __float_as_int(mx));
  }
}

// ---------------------------------------------------------------------------
// Phase A2 (merged): blocks 0..3071  : fake-quantize -> fp16 swizzled layout
//                    blocks 3072..   : x f32 -> fp16 A-fragment layout (xh)
// ---------------------------------------------------------------------------
__global__ __launch_bounds__(256) void k_prep(
    const float* __restrict__ w0, const float* __restrict__ w1,
    const float* __restrict__ w2, const float* __restrict__ w3,
    const int* __restrict__ slots,
    _Float16* __restrict__ f0, _Float16* __restrict__ f1,
    _Float16* __restrict__ f2, _Float16* __restrict__ f3,
    const float* __restrict__ x, _Float16* __restrict__ xh)
{
  if (blockIdx.x < 3072) {
    const float* srcs[4] = {w0, w1, w2, w3};
    _Float16*    dsts[4] = {f0, f1, f2, f3};
    int idx = blockIdx.x*256 + threadIdx.x;
    int m = idx / 196608;
    int e = idx - m*196608;
    float scale = __int_as_float(slots[m]) * (1.0f/127.0f);
    float w = srcs[m][e];
    float q = rintf(w/scale) * scale;
    int g = e >> 8, k = e & 255;
    int tile = g >> 4, kb = k >> 5;
    int lane = ((k >> 3) & 3)*16 + (g & 15);
    int off  = (tile*8 + kb)*512 + lane*8 + (k & 7);
    dsts[m][off] = (_Float16)q;
    return;
  }
  int n = (blockIdx.x - 3072)*256 + threadIdx.x;   // 4,194,304 total
  int t   = n >> 13;
  int rem = n & 8191;
  int bg  = rem >> 5;                              // batch row 0..255
  int k8  = rem & 31;                              // k octet 0..31
  const float4* src = (const float4*)&x[((size_t)t*256 + bg)*256 + k8*8];
  float4 v0 = src[0], v1 = src[1];
  half8 hv;
  hv[0] = (_Float16)v0.x; hv[1] = (_Float16)v0.y;
  hv[2] = (_Float16)v0.z; hv[3] = (_Float16)v0.w;
  hv[4] = (_Float16)v1.x; hv[5] = (_Float16)v1.y;
  hv[6] = (_Float16)v1.z; hv[7] = (_Float16)v1.w;
  int bb = bg >> 4, b = bg & 15, kb = k8 >> 2, lane = (k8 & 3)*16 + b;
  *(half8*)&xh[(size_t)t*65536 + (size_t)bb*4096 + kb*512 + lane*8] = hv;
}

// ---------------------------------------------------------------------------
// Fully fused pipeline: 96 blocks x 512 thr (8 waves).
//   role 0..15  : layer-1 GRU. Acquires gi1 groups via flag0,
//                 publishes h1seq progress via flag1.
//   role 16..31 : layer-2 GRU. Acquires gi2 via flag2, publishes flag3.
//   role 32..63 : gemm2 producers: h1seq @ W_ih2^T -> gi2 ring (64-step).
//   role 64..95 : gemm1 producers: xh @ W_ih1^T -> gi1 (full buffer).
// Weight fragments loaded via LDV (volatile) so they are loaded exactly once
// and stay VGPR-resident across all 512 steps.
// ---------------------------------------------------------------------------
__global__ __launch_bounds__(512, 2) void k_pipe(
    const _Float16* __restrict__ xh,
    const _Float16* __restrict__ wfih1, const float* __restrict__ bih1,
    _Float16* __restrict__ gi1, const _Float16* __restrict__ wfhh1,
    const float* __restrict__ bhh1, float* __restrict__ hc1,
    _Float16* __restrict__ h1seq,
    const _Float16* __restrict__ wfih2, const float* __restrict__ bih2,
    const float* __restrict__ bhh2, const _Float16* __restrict__ wfhh2,
    float* __restrict__ hc2, _Float16* __restrict__ gi2,
    int* __restrict__ flag0, int* __restrict__ flag1,
    int* __restrict__ flag2, int* __restrict__ flag3)
{
  __shared__ __align__(16) _Float16 hl[2][4096];   // 16 KB h dbuf (GRU roles)
  __shared__ __align__(16) _Float16 wn_l[16384];   // 32 KB: [w][nt][kb<2][512]
  const int role = blockIdx.x;
  const int tid  = threadIdx.x;
  const int w = tid >> 6, l = tid & 63, q = l >> 4, c16 = l & 15;

  if (role >= 32) {
    // ------------- gemm producers (gemm1: roles 64..95, gemm2: 32..63) -----
    const bool G1 = (role >= 64);
    const int id = G1 ? role - 64 : role - 32;
    const int bb = id >> 1, par = id & 1;
    const _Float16* Wsrc = G1 ? wfih1 : wfih2;
    const float*    bihp = G1 ? bih1  : bih2;
    const float*    bhhp = G1 ? bhh1  : bhh2;
    const _Float16* Asrc = G1 ? xh    : h1seq;
    _Float16*       gout = G1 ? gi1   : gi2;

    float bR[2], bZ[2], bN[2];
    half8 wr[2][8], wz[2][8], wn[2][8];
    #pragma unroll
    for (int nt = 0; nt < 2; nt++) {
      const int j = w*32 + nt*16 + c16;
      bR[nt] = bihp[j]       + bhhp[j];
      bZ[nt] = bihp[256 + j] + bhhp[256 + j];
      bN[nt] = bihp[512 + j];
      const _Float16* WR = Wsrc + (size_t)(2*w + nt)      *4096;
      const _Float16* WZ = Wsrc + (size_t)(16 + 2*w + nt) *4096;
      const _Float16* WN = Wsrc + (size_t)(32 + 2*w + nt) *4096;
      #pragma unroll
      for (int kb = 0; kb < 8; kb++) {
        wr[nt][kb] = LDV(&WR[(kb*64 + l)*8]);  PIN(wr[nt][kb]);
        wz[nt][kb] = LDV(&WZ[(kb*64 + l)*8]);  PIN(wz[nt][kb]);
        wn[nt][kb] = LDV(&WN[(kb*64 + l)*8]);  PIN(wn[nt][kb]);
      }
    }

    for (int g = par; g < 32; g += 2) {
      const int t0 = g*16;
      if (!G1) {
        if (tid == 0) {
          while (LD_RLX(&flag1[bb]) < t0 + 16) __builtin_amdgcn_s_sleep(10);
          if (g >= 4)
            while (LD_RLX(&flag3[bb]) < (g - 3)*16) __builtin_amdgcn_s_sleep(10);
          (void)LD_ACQ(&flag1[bb]);             // acquire: invalidate caches
        }
        __syncthreads();
      }
      for (int t = t0; t < t0 + 16; t++) {
        const _Float16* ap = Asrc + (size_t)t*65536 + (size_t)bb*4096 + l*8;
        f32x4 aR[2], aZ[2], aN[2];
        #pragma unroll
        for (int nt = 0; nt < 2; nt++) {
          aR[nt] = (f32x4){0.f,0.f,0.f,0.f};
          aZ[nt] = (f32x4){0.f,0.f,0.f,0.f};
          aN[nt] = (f32x4){0.f,0.f,0.f,0.f};
        }
        #pragma unroll
        for (int kb = 0; kb < 8; kb++) {
          half8 a = *(const half8*)&ap[kb*512];
          #pragma unroll
          for (int nt = 0; nt < 2; nt++) {
            aR[nt] = MFMA_F16(a, wr[nt][kb], aR[nt], 0, 0, 0);
            aZ[nt] = MFMA_F16(a, wz[nt][kb], aZ[nt], 0, 0, 0);
            aN[nt] = MFMA_F16(a, wn[nt][kb], aN[nt], 0, 0, 0);
          }
        }
        const size_t trow = G1 ? (size_t)t : (size_t)(t & 63);
        #pragma unroll
        for (int nt = 0; nt < 2; nt++) {
          _Float16* op = gout + (trow*256 + (2*w + nt)*16 + bb)*768 + l*12;
          half4 vR, vZ, vN;
          #pragma unroll
          for (int i = 0; i < 4; i++) {
            vR[i] = (_Float16)(aR[nt][i] + bR[nt]);
            vZ[i] = (_Float16)(aZ[nt][i] + bZ[nt]);
            vN[i] = (_Float16)(aN[nt][i] + bN[nt]);
          }
          *(half4*)(op)     = vR;
          *(half4*)(op + 4) = vZ;
          *(half4*)(op + 8) = vN;
        }
      }
      __syncthreads();                          // drains all waves' stores
      if (tid == 0) {
        if (G1) ST_REL(&flag0[bb*2 + par], t0 + 16);
        else    ST_REL(&flag2[bb*2 + par], t0 + 16);
      }
    }
    return;
  }

  // ------------------- GRU roles -------------------
  const bool L1 = (role < 16);
  const int bb = L1 ? role : role - 16;
  const int b0 = bb * 16;
  const _Float16* gi = L1 ? gi1 : gi2;
  const _Float16* Wf = L1 ? wfhh1 : wfhh2;
  const float* bhh   = L1 ? bhh1 : bhh2;
  float* hcarry      = L1 ? hc1 : hc2;

  { // stage initial h (f32 carry -> fp16 frags), 8 halves per thread
    int n = tid*8;
    int b = n >> 8, k = n & 255;
    const float4* s4 = (const float4*)&hcarry[(size_t)(b0 + b)*256 + k];
    float4 v0 = s4[0], v1 = s4[1];
    half8 hv;
    hv[0] = (_Float16)v0.x; hv[1] = (_Float16)v0.y;
    hv[2] = (_Float16)v0.z; hv[3] = (_Float16)v0.w;
    hv[4] = (_Float16)v1.x; hv[5] = (_Float16)v1.y;
    hv[6] = (_Float16)v1.z; hv[7] = (_Float16)v1.w;
    *(half8*)&hl[0][(k >> 5)*512 + (((k >> 3) & 3)*16 + b)*8] = hv;
  }

  float bN[2];
  float hprev[2][4];
  half8 wr[2][8], wz[2][8], wn[2][6];           // wn holds kb=2..7
  int   wr_off[2];
  int   gil[2];
  #pragma unroll
  for (int nt = 0; nt < 2; nt++) {
    const int j = w*32 + nt*16 + c16;
    bN[nt] = bhh[512 + j];
    #pragma unroll
    for (int i = 0; i < 4; i++)
      hprev[nt][i] = hcarry[(size_t)(b0 + q*4 + i)*256 + j];
    const _Float16* WR = Wf + (size_t)(2*w + nt)      *4096;
    const _Float16* WZ = Wf + (size_t)(16 + 2*w + nt) *4096;
    const _Float16* WN = Wf + (size_t)(32 + 2*w + nt) *4096;
    #pragma unroll
    for (int kb = 0; kb < 8; kb++) {
      wr[nt][kb] = LDV(&WR[(kb*64 + l)*8]);  PIN(wr[nt][kb]);
      wz[nt][kb] = LDV(&WZ[(kb*64 + l)*8]);  PIN(wz[nt][kb]);
    }
    #pragma unroll
    for (int kb = 2; kb < 8; kb++) {
      wn[nt][kb-2] = LDV(&WN[(kb*64 + l)*8]);  PIN(wn[nt][kb-2]);
    }
    #pragma unroll
    for (int kb = 0; kb < 2; kb++)
      *(half8*)&wn_l[((w*2 + nt)*2 + kb)*512 + l*8] =
          *(const half8*)&WN[(kb*64 + l)*8];
    wr_off[nt] = (j >> 5)*512 + ((j >> 3) & 3)*128 + (j & 7);
    gil[nt]    = ((2*w + nt)*16 + bb)*768 + l*12;
  }
  _Float16* hq = L1 ? (h1seq + (size_t)bb*4096 + tid*8) : (_Float16*)nullptr;

  __syncthreads();
  half4 pR[2], pZ[2], pN[2];                    // gi prefetch registers
  int cur = 0;
  for (int t = 0; t < 512; t++) {
    if ((t & 15) == 0) {                        // acquire gi group
      if (tid == 0) {
        int* f = L1 ? &flag0[bb*2 + ((t >> 4) & 1)]
                    : &flag2[bb*2 + ((t >> 4) & 1)];
        while (LD_RLX(f) < t + 16) __builtin_amdgcn_s_sleep(10);
        (void)LD_ACQ(f);
      }
      __syncthreads();
      const int tm = L1 ? t : (t & 63);
      const _Float16* gbase = gi + (size_t)tm*196608;
      #pragma unroll
      for (int nt = 0; nt < 2; nt++) {
        const _Float16* gp = gbase + gil[nt];
        pR[nt] = *(const half4*)(gp);
        pZ[nt] = *(const half4*)(gp + 4);
        pN[nt] = *(const half4*)(gp + 8);
      }
    }
    half4 vR[2], vZ[2], vN[2];
    #pragma unroll
    for (int nt = 0; nt < 2; nt++) {
      vR[nt] = pR[nt]; vZ[nt] = pZ[nt]; vN[nt] = pN[nt];
    }

    f32x4 aR[2], aZ[2], aN[2];
    #pragma unroll
    for (int nt = 0; nt < 2; nt++) {
      aR[nt] = (f32x4){0.f,0.f,0.f,0.f};
      aZ[nt] = (f32x4){0.f,0.f,0.f,0.f};
      aN[nt] = (f32x4){0.f,0.f,0.f,0.f};
    }
    #pragma unroll
    for (int kb = 0; kb < 8; kb++) {
      half8 a = *(const half8*)&hl[cur][kb*512 + l*8];
      #pragma unroll
      for (int nt = 0; nt < 2; nt++) {
        half8 bn = (kb < 2)
            ? *(const half8*)&wn_l[((w*2 + nt)*2 + kb)*512 + l*8]
            : wn[nt][kb-2];
        aR[nt] = MFMA_F16(a, wr[nt][kb], aR[nt], 0, 0, 0);
        aZ[nt] = MFMA_F16(a, wz[nt][kb], aZ[nt], 0, 0, 0);
        aN[nt] = MFMA_F16(a, bn,         aN[nt], 0, 0, 0);
      }
    }

    // prefetch gi(t+1) while MFMAs retire (same published group only)
    if (((t + 1) & 15) != 0) {
      const int tn = L1 ? (t + 1) : ((t + 1) & 63);
      const _Float16* gbase = gi + (size_t)tn*196608;
      #pragma unroll
      for (int nt = 0; nt < 2; nt++) {
        const _Float16* gp = gbase + gil[nt];
        pR[nt] = *(const half4*)(gp);
        pZ[nt] = *(const half4*)(gp + 4);
        pN[nt] = *(const half4*)(gp + 8);
      }
    }

    const int nxt = cur ^ 1;
    #pragma unroll
    for (int nt = 0; nt < 2; nt++) {
      #pragma unroll
      for (int i = 0; i < 4; i++) {
        float r  = sigm_f(aR[nt][i] + (float)vR[nt][i]);
        float z  = sigm_f(aZ[nt][i] + (float)vZ[nt][i]);
        float nn = tanh_fast((float)vN[nt][i] + r*(aN[nt][i] + bN[nt]));
        float hp = nn + z*(hprev[nt][i] - nn);  // (1-z)*n + z*h
        hprev[nt][i] = hp;
        hl[nxt][wr_off[nt] + (q*4 + i)*8] = (_Float16)hp;
      }
    }

    if ((t & 15) == 0 && t > 0) {
      bar_strong();                             // drains hq stores <= t-1
      if (tid == 0) {
        if (L1) ST_REL(&flag1[bb], t);          // steps 0..t-1 published
        else    ST_REL(&flag3[bb], t);          // steps 0..t-1 consumed
      }
    } else {
      bar_weak();                               // LDS visibility only
    }
    if (L1)
      *(half8*)&hq[(size_t)t*65536] = *(const half8*)&hl[nxt][tid*8];
    cur = nxt;
  }
  bar_strong();                                 // drain hq(511)
  if (tid == 0) {
    if (L1) ST_REL(&flag1[bb], 512);
    else    ST_REL(&flag3[bb], 512);
  }

  #pragma unroll
  for (int nt = 0; nt < 2; nt++) {
    const int j = w*32 + nt*16 + c16;
    #pragma unroll
    for (int i = 0; i < 4; i++)
      hcarry[(size_t)(b0 + q*4 + i)*256 + j] = hprev[nt][i];
  }
}

// ---------------------------------------------------------------------------
extern "C" void kernel_launch(void* const* d_in, const int* in_sizes, int n_in,
                              void* d_out, int out_size, void* d_ws, size_t ws_size,
                              hipStream_t stream)
{
  const float* x     = (const float*)d_in[0];
  const float* h1_0  = (const float*)d_in[1];
  const float* h2_0  = (const float*)d_in[2];
  const float* w_ih1 = (const float*)d_in[3];
  const float* w_hh1 = (const float*)d_in[4];
  const float* b_ih1 = (const float*)d_in[5];
  const float* b_hh1 = (const float*)d_in[6];
  const float* w_ih2 = (const float*)d_in[7];
  const float* w_hh2 = (const float*)d_in[8];
  const float* b_ih2 = (const float*)d_in[9];
  const float* b_hh2 = (const float*)d_in[10];

  char* ws = (char*)d_ws;
  size_t off = 0;
  auto alloc = [&](size_t bytes) -> void* {
    void* p = ws + off; off += (bytes + 255) & ~(size_t)255; return p;
  };
  int*      slots   = (int*)     alloc(16);
  _Float16* wf_ih1  = (_Float16*)alloc(196608*2);
  _Float16* wf_hh1  = (_Float16*)alloc(196608*2);
  _Float16* wf_ih2  = (_Float16*)alloc(196608*2);
  _Float16* wf_hh2  = (_Float16*)alloc(196608*2);
  float*    hc1     = (float*)   alloc(256*256*4);
  float*    hc2     = (float*)   alloc(256*256*4);
  int*      flag0   = (int*)     alloc(32*4);
  int*      flag1   = (int*)     alloc(16*4);
  int*      flag2   = (int*)     alloc(32*4);
  int*      flag3   = (int*)     alloc(16*4);
  _Float16* gi1     = (_Float16*)alloc((size_t)512*393216);   // 201 MB
  _Float16* h1seq   = (_Float16*)alloc((size_t)512*131072);   //  67 MB
  _Float16* gi2     = (_Float16*)alloc((size_t)64*393216);    //  25 MB ring
  _Float16* xhbuf   = (_Float16*)alloc((size_t)512*131072);   //  67 MB

  k_maxabs<<<128, 256, 0, stream>>>(w_ih1, w_hh1, w_ih2, w_hh2, 196608, slots);
  k_prep  <<<19456, 256, 0, stream>>>(w_ih1, w_hh1, w_ih2, w_hh2, slots,
                                      wf_ih1, wf_hh1, wf_ih2, wf_hh2, x, xhbuf);
  (void)hipMemcpyAsync(hc1, h1_0, 256*256*4, hipMemcpyDeviceToDevice, stream);
  (void)hipMemcpyAsync(hc2, h2_0, 256*256*4, hipMemcpyDeviceToDevice, stream);

  k_pipe<<<96, 512, 0, stream>>>(xhbuf, wf_ih1, b_ih1, gi1, wf_hh1, b_hh1,
                                 hc1, h1seq, wf_ih2, b_ih2, b_hh2, wf_hh2,
                                 hc2, gi2, flag0, flag1, flag2, flag3);

  (void)hipMemcpyAsync(d_out, hc2, 256*256*4, hipMemcpyDeviceToDevice, stream);
}

// Round 8
// 1338.391 us; speedup vs baseline: 1.6246x; 1.0004x over previous
//
#include <hip/hip_runtime.h>
#include <hip/hip_fp16.h>
#include <cstdint>

typedef _Float16 half8 __attribute__((ext_vector_type(8)));
typedef _Float16 half4 __attribute__((ext_vector_type(4)));
typedef float f32x4 __attribute__((ext_vector_type(4)));

#define MFMA_F16 __builtin_amdgcn_mfma_f32_16x16x32_f16
#define PIN(x)   asm volatile("" : "+v"(x))
#define LD_RLX(p)   __hip_atomic_load((p),  __ATOMIC_RELAXED, __HIP_MEMORY_SCOPE_AGENT)
#define LD_ACQ(p)   __hip_atomic_load((p),  __ATOMIC_ACQUIRE, __HIP_MEMORY_SCOPE_AGENT)
#define ST_REL(p,v) __hip_atomic_store((p),(v), __ATOMIC_RELEASE, __HIP_MEMORY_SCOPE_AGENT)

__device__ __forceinline__ float fast_rcp(float x){
#if __has_builtin(__builtin_amdgcn_rcpf)
  return __builtin_amdgcn_rcpf(x);
#else
  return 1.0f/x;
#endif
}
__device__ __forceinline__ float fast_exp2(float x){
#if __has_builtin(__builtin_amdgcn_exp2f)
  return __builtin_amdgcn_exp2f(x);
#else
  return exp2f(x);
#endif
}
__device__ __forceinline__ float sigm_f(float x){
  return fast_rcp(1.0f + fast_exp2(-1.44269504f*x));
}
__device__ __forceinline__ float tanh_fast(float x){
  float e = fast_exp2(-2.88539008f*x);            // e^(-2x)
  return fmaf(2.0f, fast_rcp(1.0f + e), -1.0f);   // 2/(1+e) - 1
}

// Weak barrier: LDS visibility only. Strong barrier: full vmcnt drain,
// used only at 16-step flag boundaries (release/acquire protocol).
__device__ __forceinline__ void bar_weak(){
  asm volatile("s_waitcnt lgkmcnt(0)" ::: "memory");
  __builtin_amdgcn_s_barrier();
  asm volatile("" ::: "memory");
}
__device__ __forceinline__ void bar_strong(){
  asm volatile("s_waitcnt vmcnt(0) lgkmcnt(0)" ::: "memory");
  __builtin_amdgcn_s_barrier();
  asm volatile("" ::: "memory");
}

// Self-quantizing fragment load: extract the MFMA B-fragment (tile, kb) for
// lane l straight from the row-major f32 weight matrix and fake-quantize it
// (bit-identical to the old k_quant: rintf(w/scale)*scale). One-time cost at
// role startup; removes the k_quant pass + wf buffers from the prologue.
__device__ __forceinline__ half8 qfrag(const float* __restrict__ W, int tile,
                                       int kb, int l, float scale){
  int row = tile*16 + (l & 15);
  int k0  = kb*32 + (l >> 4)*8;
  const float4* p = (const float4*)&W[row*256 + k0];
  float4 a = p[0], b = p[1];
  half8 h;
  h[0] = (_Float16)(rintf(a.x/scale)*scale);
  h[1] = (_Float16)(rintf(a.y/scale)*scale);
  h[2] = (_Float16)(rintf(a.z/scale)*scale);
  h[3] = (_Float16)(rintf(a.w/scale)*scale);
  h[4] = (_Float16)(rintf(b.x/scale)*scale);
  h[5] = (_Float16)(rintf(b.y/scale)*scale);
  h[6] = (_Float16)(rintf(b.z/scale)*scale);
  h[7] = (_Float16)(rintf(b.w/scale)*scale);
  return h;
}

// ---------------------------------------------------------------------------
// Phase A1: per-matrix max|w| (4 matrices of 768x256)
// ---------------------------------------------------------------------------
__global__ __launch_bounds__(256) void k_maxabs(
    const float* __restrict__ w0, const float* __restrict__ w1,
    const float* __restrict__ w2, const float* __restrict__ w3,
    int n, int* __restrict__ slots)
{
  const float* srcs[4] = {w0, w1, w2, w3};
  int m    = blockIdx.x >> 5;
  int part = blockIdx.x & 31;
  const float* w = srcs[m];
  float loc = 0.0f;
  for (int i = part*256 + threadIdx.x; i < n; i += 32*256)
    loc = fmaxf(loc, fabsf(w[i]));
  for (int off = 32; off; off >>= 1)
    loc = fmaxf(loc, __shfl_down(loc, off, 64));
  __shared__ float red[4];
  int wv = threadIdx.x >> 6;
  if ((threadIdx.x & 63) == 0) red[wv] = loc;
  __syncthreads();
  if (threadIdx.x == 0) {
    float mx = fmaxf(fmaxf(red[0], red[1]), fmaxf(red[2], red[3]));
    atomicMax(&slots[m], __float_as_int(mx));
  }
}

// ---------------------------------------------------------------------------
// Phase A2: x f32 -> fp16 in h1seq-style MFMA A-fragment layout.
// ---------------------------------------------------------------------------
__global__ __launch_bounds__(256) void k_xcast(
    const float* __restrict__ x, _Float16* __restrict__ xh)
{
  int n = blockIdx.x*256 + threadIdx.x;           // 4,194,304 total
  int t   = n >> 13;
  int rem = n & 8191;
  int bg  = rem >> 5;                             // batch row 0..255
  int k8  = rem & 31;                             // k octet 0..31
  const float4* src = (const float4*)&x[((size_t)t*256 + bg)*256 + k8*8];
  float4 v0 = src[0], v1 = src[1];
  half8 hv;
  hv[0] = (_Float16)v0.x; hv[1] = (_Float16)v0.y;
  hv[2] = (_Float16)v0.z; hv[3] = (_Float16)v0.w;
  hv[4] = (_Float16)v1.x; hv[5] = (_Float16)v1.y;
  hv[6] = (_Float16)v1.z; hv[7] = (_Float16)v1.w;
  int bb = bg >> 4, b = bg & 15, kb = k8 >> 2, lane = (k8 & 3)*16 + b;
  *(half8*)&xh[(size_t)t*65536 + (size_t)bb*4096 + kb*512 + lane*8] = hv;
}

// ---------------------------------------------------------------------------
// Fully fused pipeline: 96 blocks x 512 thr (8 waves).
//   role 0..15  : layer-1 GRU. Acquires gi1 (ring) via flag0, publishes flag1.
//   role 16..31 : layer-2 GRU. Acquires gi2 (ring) via flag2, publishes flag3.
//   role 32..63 : gemm2 producers: h1seq @ W_ih2^T -> gi2 ring (64-step),
//                 back-pressure via flag3.
//   role 64..95 : gemm1 producers: xh @ W_ih1^T -> gi1 ring (64-step),
//                 back-pressure via flag1 (L1 progress; window = 4 groups).
// Both gi buffers are 25 MB rings -> total inter-role working set ~184 MB
// fits in the 256 MB L3; gi traffic no longer round-trips HBM.
// All roles self-quantize their weight fragments at startup (bit-identical
// to the old k_quant pass).
// ---------------------------------------------------------------------------
__global__ __launch_bounds__(512, 2) void k_pipe(
    const _Float16* __restrict__ xh,
    const float* __restrict__ wih1, const float* __restrict__ bih1,
    _Float16* __restrict__ gi1, const float* __restrict__ whh1,
    const float* __restrict__ bhh1, float* __restrict__ hc1,
    _Float16* __restrict__ h1seq,
    const float* __restrict__ wih2, const float* __restrict__ bih2,
    const float* __restrict__ bhh2, const float* __restrict__ whh2,
    float* __restrict__ hc2, _Float16* __restrict__ gi2,
    const int* __restrict__ slots,
    int* __restrict__ flag0, int* __restrict__ flag1,
    int* __restrict__ flag2, int* __restrict__ flag3)
{
  __shared__ __align__(16) _Float16 hl[2][4096];   // 16 KB h dbuf (GRU roles)
  __shared__ __align__(16) _Float16 wn_l[16384];   // 32 KB: [w][nt][kb<2][512]
  const int role = blockIdx.x;
  const int tid  = threadIdx.x;
  const int w = tid >> 6, l = tid & 63, q = l >> 4, c16 = l & 15;

  if (role >= 32) {
    // ------------- gemm producers (gemm1: roles 64..95, gemm2: 32..63) -----
    const bool G1 = (role >= 64);
    const int id = G1 ? role - 64 : role - 32;
    const int bb = id >> 1, par = id & 1;
    const float*    Wsrc = G1 ? wih1  : wih2;
    const float*    bihp = G1 ? bih1  : bih2;
    const float*    bhhp = G1 ? bhh1  : bhh2;
    const _Float16* Asrc = G1 ? xh    : h1seq;
    _Float16*       gout = G1 ? gi1   : gi2;
    const float sc = __int_as_float(slots[G1 ? 0 : 2]) * (1.0f/127.0f);

    float bR[2], bZ[2], bN[2];
    half8 wr[2][8], wz[2][8], wn[2][8];
    #pragma unroll
    for (int nt = 0; nt < 2; nt++) {
      const int j = w*32 + nt*16 + c16;
      bR[nt] = bihp[j]       + bhhp[j];
      bZ[nt] = bihp[256 + j] + bhhp[256 + j];
      bN[nt] = bihp[512 + j];
      #pragma unroll
      for (int kb = 0; kb < 8; kb++) {
        wr[nt][kb] = qfrag(Wsrc,      2*w + nt, kb, l, sc);  PIN(wr[nt][kb]);
        wz[nt][kb] = qfrag(Wsrc, 16 + 2*w + nt, kb, l, sc);  PIN(wz[nt][kb]);
        wn[nt][kb] = qfrag(Wsrc, 32 + 2*w + nt, kb, l, sc);  PIN(wn[nt][kb]);
      }
    }

    for (int g = par; g < 32; g += 2) {
      const int t0 = g*16;
      if (tid == 0) {
        if (!G1) {
          while (LD_RLX(&flag1[bb]) < t0 + 16) __builtin_amdgcn_s_sleep(10);
          if (g >= 4)
            while (LD_RLX(&flag3[bb]) < (g - 3)*16) __builtin_amdgcn_s_sleep(10);
          (void)LD_ACQ(&flag1[bb]);             // acquire: h1seq visible
        } else if (g >= 4) {
          // gi1 ring back-pressure: L1 must have consumed group g-4
          while (LD_RLX(&flag1[bb]) < (g - 3)*16) __builtin_amdgcn_s_sleep(10);
          (void)LD_ACQ(&flag1[bb]);             // order ring writes after
        }
      }
      __syncthreads();
      for (int t = t0; t < t0 + 16; t++) {
        const _Float16* ap = Asrc + (size_t)t*65536 + (size_t)bb*4096 + l*8;
        f32x4 aR[2], aZ[2], aN[2];
        #pragma unroll
        for (int nt = 0; nt < 2; nt++) {
          aR[nt] = (f32x4){0.f,0.f,0.f,0.f};
          aZ[nt] = (f32x4){0.f,0.f,0.f,0.f};
          aN[nt] = (f32x4){0.f,0.f,0.f,0.f};
        }
        #pragma unroll
        for (int kb = 0; kb < 8; kb++) {
          half8 a = *(const half8*)&ap[kb*512];
          #pragma unroll
          for (int nt = 0; nt < 2; nt++) {
            aR[nt] = MFMA_F16(a, wr[nt][kb], aR[nt], 0, 0, 0);
            aZ[nt] = MFMA_F16(a, wz[nt][kb], aZ[nt], 0, 0, 0);
            aN[nt] = MFMA_F16(a, wn[nt][kb], aN[nt], 0, 0, 0);
          }
        }
        const size_t trow = (size_t)(t & 63);     // both gi are 64-step rings
        #pragma unroll
        for (int nt = 0; nt < 2; nt++) {
          _Float16* op = gout + (trow*256 + (2*w + nt)*16 + bb)*768 + l*12;
          half4 vR, vZ, vN;
          #pragma unroll
          for (int i = 0; i < 4; i++) {
            vR[i] = (_Float16)(aR[nt][i] + bR[nt]);
            vZ[i] = (_Float16)(aZ[nt][i] + bZ[nt]);
            vN[i] = (_Float16)(aN[nt][i] + bN[nt]);
          }
          *(half4*)(op)     = vR;
          *(half4*)(op + 4) = vZ;
          *(half4*)(op + 8) = vN;
        }
      }
      __syncthreads();                          // drains all waves' stores
      if (tid == 0) {
        if (G1) ST_REL(&flag0[bb*2 + par], t0 + 16);
        else    ST_REL(&flag2[bb*2 + par], t0 + 16);
      }
    }
    return;
  }

  // ------------------- GRU roles -------------------
  const bool L1 = (role < 16);
  const int bb = L1 ? role : role - 16;
  const int b0 = bb * 16;
  const _Float16* gi = L1 ? gi1 : gi2;
  const float* Wf    = L1 ? whh1 : whh2;
  const float* bhh   = L1 ? bhh1 : bhh2;
  float* hcarry      = L1 ? hc1 : hc2;
  const float sc     = __int_as_float(slots[L1 ? 1 : 3]) * (1.0f/127.0f);

  { // stage initial h (f32 carry -> fp16 frags), 8 halves per thread
    int n = tid*8;
    int b = n >> 8, k = n & 255;
    const float4* s4 = (const float4*)&hcarry[(size_t)(b0 + b)*256 + k];
    float4 v0 = s4[0], v1 = s4[1];
    half8 hv;
    hv[0] = (_Float16)v0.x; hv[1] = (_Float16)v0.y;
    hv[2] = (_Float16)v0.z; hv[3] = (_Float16)v0.w;
    hv[4] = (_Float16)v1.x; hv[5] = (_Float16)v1.y;
    hv[6] = (_Float16)v1.z; hv[7] = (_Float16)v1.w;
    *(half8*)&hl[0][(k >> 5)*512 + (((k >> 3) & 3)*16 + b)*8] = hv;
  }

  float bN[2];
  float hprev[2][4];
  half8 wr[2][8], wz[2][8], wn[2][6];           // wn holds kb=2..7
  int   wr_off[2];
  int   gil[2];
  #pragma unroll
  for (int nt = 0; nt < 2; nt++) {
    const int j = w*32 + nt*16 + c16;
    bN[nt] = bhh[512 + j];
    #pragma unroll
    for (int i = 0; i < 4; i++)
      hprev[nt][i] = hcarry[(size_t)(b0 + q*4 + i)*256 + j];
    #pragma unroll
    for (int kb = 0; kb < 8; kb++) {
      wr[nt][kb] = qfrag(Wf,      2*w + nt, kb, l, sc);  PIN(wr[nt][kb]);
      wz[nt][kb] = qfrag(Wf, 16 + 2*w + nt, kb, l, sc);  PIN(wz[nt][kb]);
    }
    #pragma unroll
    for (int kb = 2; kb < 8; kb++) {
      wn[nt][kb-2] = qfrag(Wf, 32 + 2*w + nt, kb, l, sc);  PIN(wn[nt][kb-2]);
    }
    #pragma unroll
    for (int kb = 0; kb < 2; kb++)
      *(half8*)&wn_l[((w*2 + nt)*2 + kb)*512 + l*8] =
          qfrag(Wf, 32 + 2*w + nt, kb, l, sc);
    wr_off[nt] = (j >> 5)*512 + ((j >> 3) & 3)*128 + (j & 7);
    gil[nt]    = ((2*w + nt)*16 + bb)*768 + l*12;
  }
  _Float16* hq = L1 ? (h1seq + (size_t)bb*4096 + tid*8) : (_Float16*)nullptr;

  __syncthreads();
  half4 pR[2], pZ[2], pN[2];                    // gi prefetch registers
  int cur = 0;
  for (int t = 0; t < 512; t++) {
    if ((t & 15) == 0) {                        // acquire gi group
      if (tid == 0) {
        int* f = L1 ? &flag0[bb*2 + ((t >> 4) & 1)]
                    : &flag2[bb*2 + ((t >> 4) & 1)];
        while (LD_RLX(f) < t + 16) __builtin_amdgcn_s_sleep(10);
        (void)LD_ACQ(f);
      }
      __syncthreads();
      const int tm = t & 63;
      const _Float16* gbase = gi + (size_t)tm*196608;
      #pragma unroll
      for (int nt = 0; nt < 2; nt++) {
        const _Float16* gp = gbase + gil[nt];
        pR[nt] = *(const half4*)(gp);
        pZ[nt] = *(const half4*)(gp + 4);
        pN[nt] = *(const half4*)(gp + 8);
      }
    }
    half4 vR[2], vZ[2], vN[2];
    #pragma unroll
    for (int nt = 0; nt < 2; nt++) {
      vR[nt] = pR[nt]; vZ[nt] = pZ[nt]; vN[nt] = pN[nt];
    }

    f32x4 aR[2], aZ[2], aN[2];
    #pragma unroll
    for (int nt = 0; nt < 2; nt++) {
      aR[nt] = (f32x4){0.f,0.f,0.f,0.f};
      aZ[nt] = (f32x4){0.f,0.f,0.f,0.f};
      aN[nt] = (f32x4){0.f,0.f,0.f,0.f};
    }
    #pragma unroll
    for (int kb = 0; kb < 8; kb++) {
      half8 a = *(const half8*)&hl[cur][kb*512 + l*8];
      #pragma unroll
      for (int nt = 0; nt < 2; nt++) {
        half8 bn = (kb < 2)
            ? *(const half8*)&wn_l[((w*2 + nt)*2 + kb)*512 + l*8]
            : wn[nt][kb-2];
        aR[nt] = MFMA_F16(a, wr[nt][kb], aR[nt], 0, 0, 0);
        aZ[nt] = MFMA_F16(a, wz[nt][kb], aZ[nt], 0, 0, 0);
        aN[nt] = MFMA_F16(a, bn,         aN[nt], 0, 0, 0);
      }
    }

    // prefetch gi(t+1) while MFMAs retire (same published group only)
    if (((t + 1) & 15) != 0) {
      const int tn = (t + 1) & 63;
      const _Float16* gbase = gi + (size_t)tn*196608;
      #pragma unroll
      for (int nt = 0; nt < 2; nt++) {
        const _Float16* gp = gbase + gil[nt];
        pR[nt] = *(const half4*)(gp);
        pZ[nt] = *(const half4*)(gp + 4);
        pN[nt] = *(const half4*)(gp + 8);
      }
    }

    const int nxt = cur ^ 1;
    #pragma unroll
    for (int nt = 0; nt < 2; nt++) {
      #pragma unroll
      for (int i = 0; i < 4; i++) {
        float r  = sigm_f(aR[nt][i] + (float)vR[nt][i]);
        float z  = sigm_f(aZ[nt][i] + (float)vZ[nt][i]);
        float nn = tanh_fast((float)vN[nt][i] + r*(aN[nt][i] + bN[nt]));
        float hp = nn + z*(hprev[nt][i] - nn);  // (1-z)*n + z*h
        hprev[nt][i] = hp;
        hl[nxt][wr_off[nt] + (q*4 + i)*8] = (_Float16)hp;
      }
    }

    if ((t & 15) == 0 && t > 0) {
      bar_strong();                             // drains hq stores + gi reads
      if (tid == 0) {
        if (L1) ST_REL(&flag1[bb], t);          // steps 0..t-1 published,
        else    ST_REL(&flag3[bb], t);          // gi ring slots < t free
      }
    } else {
      bar_weak();                               // LDS visibility only
    }
    if (L1)
      *(half8*)&hq[(size_t)t*65536] = *(const half8*)&hl[nxt][tid*8];
    cur = nxt;
  }
  bar_strong();                                 // drain hq(511)
  if (tid == 0) {
    if (L1) ST_REL(&flag1[bb], 512);
    else    ST_REL(&flag3[bb], 512);
  }

  #pragma unroll
  for (int nt = 0; nt < 2; nt++) {
    const int j = w*32 + nt*16 + c16;
    #pragma unroll
    for (int i = 0; i < 4; i++)
      hcarry[(size_t)(b0 + q*4 + i)*256 + j] = hprev[nt][i];
  }
}

// ---------------------------------------------------------------------------
extern "C" void kernel_launch(void* const* d_in, const int* in_sizes, int n_in,
                              void* d_out, int out_size, void* d_ws, size_t ws_size,
                              hipStream_t stream)
{
  const float* x     = (const float*)d_in[0];
  const float* h1_0  = (const float*)d_in[1];
  const float* h2_0  = (const float*)d_in[2];
  const float* w_ih1 = (const float*)d_in[3];
  const float* w_hh1 = (const float*)d_in[4];
  const float* b_ih1 = (const float*)d_in[5];
  const float* b_hh1 = (const float*)d_in[6];
  const float* w_ih2 = (const float*)d_in[7];
  const float* w_hh2 = (const float*)d_in[8];
  const float* b_ih2 = (const float*)d_in[9];
  const float* b_hh2 = (const float*)d_in[10];

  char* ws = (char*)d_ws;
  size_t off = 0;
  auto alloc = [&](size_t bytes) -> void* {
    void* p = ws + off; off += (bytes + 255) & ~(size_t)255; return p;
  };
  int*      slots   = (int*)     alloc(16);
  float*    hc1     = (float*)   alloc(256*256*4);
  float*    hc2     = (float*)   alloc(256*256*4);
  int*      flag0   = (int*)     alloc(32*4);
  int*      flag1   = (int*)     alloc(16*4);
  int*      flag2   = (int*)     alloc(32*4);
  int*      flag3   = (int*)     alloc(16*4);
  _Float16* gi1     = (_Float16*)alloc((size_t)64*393216);    //  25 MB ring
  _Float16* h1seq   = (_Float16*)alloc((size_t)512*131072);   //  67 MB
  _Float16* gi2     = (_Float16*)alloc((size_t)64*393216);    //  25 MB ring
  _Float16* xhbuf   = (_Float16*)alloc((size_t)512*131072);   //  67 MB

  k_maxabs<<<128, 256, 0, stream>>>(w_ih1, w_hh1, w_ih2, w_hh2, 196608, slots);
  k_xcast <<<16384, 256, 0, stream>>>(x, xhbuf);
  (void)hipMemcpyAsync(hc1, h1_0, 256*256*4, hipMemcpyDeviceToDevice, stream);
  (void)hipMemcpyAsync(hc2, h2_0, 256*256*4, hipMemcpyDeviceToDevice, stream);

  k_pipe<<<96, 512, 0, stream>>>(xhbuf, w_ih1, b_ih1, gi1, w_hh1, b_hh1,
                                 hc1, h1seq, w_ih2, b_ih2, b_hh2, w_hh2,
                                 hc2, gi2, slots, flag0, flag1, flag2, flag3);

  (void)hipMemcpyAsync(d_out, hc2, 256*256*4, hipMemcpyDeviceToDevice, stream);
}